// Round 3
// baseline (299.280 us; speedup 1.0000x reference)
//
#include <hip/hip_runtime.h>

#define DIM 1024
#define BATCH 4
#define SEQ 4096
#define NH 16
#define HD 64
#define KP 256

typedef float f32x4 __attribute__((ext_vector_type(4)));
typedef _Float16 half8 __attribute__((ext_vector_type(8)));

__device__ __forceinline__ void gll16(const void* g, void* l) {
  __builtin_amdgcn_global_load_lds(
      (const __attribute__((address_space(1))) void*)g,
      (__attribute__((address_space(3))) void*)l, 16, 0, 0);
}

// DPP row_ror:n within 16-lane rows (VALU-latency cross-lane; our reduction
// groups are exactly the 16-lane DPP rows). ctrl = 0x120|n.
#define DPPF(v, ctrl)                                                        \
  __builtin_bit_cast(float, __builtin_amdgcn_mov_dpp(                        \
                                __builtin_bit_cast(int, v), ctrl, 0xF, 0xF, true))

// ---- fp32 -> fp16 elementwise convert, 8 elems/thread ----
__global__ void k_cvt(const float* __restrict__ s, _Float16* __restrict__ d) {
  int i = (blockIdx.x * 256 + threadIdx.x) * 8;
  f32x4 a = *(const f32x4*)(s + i);
  f32x4 b = *(const f32x4*)(s + i + 4);
  half8 h;
  h[0] = a[0]; h[1] = a[1]; h[2] = a[2]; h[3] = a[3];
  h[4] = b[0]; h[5] = b[1]; h[6] = b[2]; h[7] = b[3];
  *(half8*)(d + i) = h;
}

// Wq and Wo converts merged: grid 1024 blocks
__global__ void k_cvtw(const float* __restrict__ Wq, const float* __restrict__ Wo,
                       _Float16* __restrict__ Wq_h, _Float16* __restrict__ Wo_h) {
  int bb = blockIdx.x;
  const float* s = (bb < 512) ? Wq : Wo;
  _Float16* d = (bb < 512) ? Wq_h : Wo_h;
  int i = ((bb & 511) * 256 + threadIdx.x) * 8;
  f32x4 a = *(const f32x4*)(s + i);
  f32x4 b = *(const f32x4*)(s + i + 4);
  half8 h;
  h[0] = a[0]; h[1] = a[1]; h[2] = a[2]; h[3] = a[3];
  h[4] = b[0]; h[5] = b[1]; h[6] = b[2]; h[7] = b[3];
  *(half8*)(d + i) = h;
}

// misc small work merged: grid 88 blocks
__global__ void k_misc(const float* __restrict__ E, const float* __restrict__ F,
                       _Float16* __restrict__ E_h, _Float16* __restrict__ Ft,
                       float* __restrict__ xsum) {
  int bb = blockIdx.x;
  if (bb < 16) {
    xsum[bb * 256 + threadIdx.x] = 0.f;
  } else if (bb < 24) {
    int i = ((bb - 16) * 256 + threadIdx.x) * 8;
    f32x4 a = *(const f32x4*)(E + i);
    f32x4 b = *(const f32x4*)(E + i + 4);
    half8 h;
    h[0] = a[0]; h[1] = a[1]; h[2] = a[2]; h[3] = a[3];
    h[4] = b[0]; h[5] = b[1]; h[6] = b[2]; h[7] = b[3];
    *(half8*)(E_h + i) = h;
  } else {
    int i = (bb - 24) * 256 + threadIdx.x;  // 16384
    int k = i >> 6, d = i & 63;
    Ft[d * KP + (k & 15) * 16 + (k >> 4)] = (_Float16)F[i];
  }
}

// xsum[b,c] = sum_n x[b,n,c]; reads fp16 x_h; grid (4,B,32)
__global__ void k_xsum(const _Float16* __restrict__ xh, float* __restrict__ xs) {
  int c = blockIdx.x * 256 + threadIdx.x;
  int b = blockIdx.y;
  int n0 = blockIdx.z * 128;
  const _Float16* p = xh + (size_t)(b * SEQ + n0) * DIM + c;
  float s = 0.f;
  #pragma unroll 8
  for (int i = 0; i < 128; i++) s += (float)p[i * DIM];
  atomicAdd(&xs[b * DIM + c], s);
}

// Sk[b,c] = xsum[b,:]@Wk[c,:], Sv likewise. One wave per output dot.
__global__ void k_sksv(const float* __restrict__ xs, const float* __restrict__ Wk,
                       const float* __restrict__ Wv, float* __restrict__ Sk,
                       float* __restrict__ Sv) {
  int idx = blockIdx.x * 4 + (threadIdx.x >> 6);
  int lane = threadIdx.x & 63;
  int kv = idx >> 12;
  int rem = idx & 4095;
  int b = rem >> 10, c = rem & 1023;
  const float* W = (kv ? Wv : Wk) + c * DIM;
  const float* xp = xs + b * DIM;
  float a = 0.f;
  #pragma unroll
  for (int i = 0; i < 16; i++) a += xp[lane + i * 64] * W[lane + i * 64];
  for (int off = 32; off; off >>= 1) a += __shfl_down(a, off);
  if (lane == 0) (kv ? Sv : Sk)[rem] = a;
}

// ---- fp16 MFMA GEMM, round 5: 256x256 tile, ONE barrier per K-tile ----
// Round-2 postmortem: 4 barriers + 2 full lgkmcnt(0) drains per BK-32 tile
// serialized the 96KB/tile LDS drain against the 1242cy/tile MFMA block
// (every wave parked at the same lgkmcnt(0)). This round: single-barrier
// tiles, AITER-style ~32 MFMA per barrier. Per tile: issue 4 gll16 (tile
// t+2, ring-of-4) + 12 ds_read_b128 fragments, 32 MFMA (compiler inserts
// counted lgkmcnt before operand use), vmcnt(4) (keep newest 4 in flight,
// drain tile-(t+1)'s), one s_barrier. Waves free-run within a tile so one
// wave's MFMA hides another's LDS drain (m114). Lifetimes: buf rs=(t+2)&3
// last read at t-2 (completed before that tile's barrier); tile t+1 loads
// drained by the end-of-t vmcnt(4). Chunk XOR swizzle (conflict-free,
// verified round 1-2) retained.
// MODE 0: out fp16 = acc * sb[b*DIM+col] * 0.125 * log2e  (Q proj)
// MODE 1: out fp32 = acc + sb[col]                        (out proj + bias)
template <int MODE>
__global__ __launch_bounds__(512, 2) void k_gemm(const _Float16* __restrict__ A,
                                                 const _Float16* __restrict__ Bw,
                                                 void* __restrict__ Cout,
                                                 const float* __restrict__ sb) {
  __shared__ _Float16 sh[4][2][8192];  // [ring][A=0/B=1][256 rows x 32 k]
  const int tid = threadIdx.x;
  const int w = tid >> 6, l = tid & 63;
  const int q4 = l >> 4, mm = l & 15;
  const int wm = w & 1, wn = w >> 1;
  const int m0 = blockIdx.x * 256, n0 = blockIdx.y * 256;
  f32x4 acc[8][4] = {};

  // staging: lds chunk c = w*128+u*64+l -> row=c>>2, chunk=c&3; source is
  // pre-swizzled so LDS[row][c] = global[row][c ^ ((row>>1)&3)].
  const int schunk = ((l & 3) ^ ((l >> 3) & 3)) * 8;
  const _Float16* Ag = A + (size_t)(m0 + w * 32 + (l >> 2)) * DIM + schunk;
  const _Float16* Bg = Bw + (size_t)(n0 + w * 32 + (l >> 2)) * DIM + schunk;
  const int sdst = w * 1024;
  // reader: global chunk q4 of row r is stored at chunk q4 ^ ((r>>1)&3);
  // (r>>1)&3 == (mm>>1)&3 for all frag rows.
  const int csw = (q4 ^ ((mm >> 1) & 3)) * 8;
  const int rdo_a = (wm * 128 + mm) * 32 + csw;
  const int rdo_b = (wn * 64 + mm) * 32 + csw;

  // prologue: stage K-tiles 0 and 1; wait tile 0 only (4 newest in flight)
  gll16(Ag, &sh[0][0][sdst]);
  gll16(Ag + 16 * DIM, &sh[0][0][sdst + 512]);
  gll16(Bg, &sh[0][1][sdst]);
  gll16(Bg + 16 * DIM, &sh[0][1][sdst + 512]);
  gll16(Ag + 32, &sh[1][0][sdst]);
  gll16(Ag + 32 + 16 * DIM, &sh[1][0][sdst + 512]);
  gll16(Bg + 32, &sh[1][1][sdst]);
  gll16(Bg + 32 + 16 * DIM, &sh[1][1][sdst + 512]);
  asm volatile("s_waitcnt vmcnt(4)" ::: "memory");
  __builtin_amdgcn_s_barrier();

  #pragma unroll 4
  for (int t = 0; t < 32; t++) {
    const int s = t & 3, rs = (t + 2) & 3;
    // stage tile t+2 first: vmem queue starts earliest
    if (t < 30) {
      const int kn = (t + 2) * 32;
      gll16(Ag + kn, &sh[rs][0][sdst]);
      gll16(Ag + kn + 16 * DIM, &sh[rs][0][sdst + 512]);
      gll16(Bg + kn, &sh[rs][1][sdst]);
      gll16(Bg + kn + 16 * DIM, &sh[rs][1][sdst + 512]);
    }
    const _Float16* Ap = &sh[s][0][rdo_a];
    const _Float16* Bp = &sh[s][1][rdo_b];
    half8 bv[4], av[8];
    #pragma unroll
    for (int i = 0; i < 4; i++) bv[i] = *(const half8*)(Bp + i * 512);
    #pragma unroll
    for (int i = 0; i < 8; i++) av[i] = *(const half8*)(Ap + i * 512);
    __builtin_amdgcn_s_setprio(1);
    #pragma unroll
    for (int mt = 0; mt < 8; mt++)
      #pragma unroll
      for (int nt = 0; nt < 4; nt++)
        acc[mt][nt] = __builtin_amdgcn_mfma_f32_16x16x32_f16(av[mt], bv[nt], acc[mt][nt], 0, 0, 0);
    __builtin_amdgcn_s_setprio(0);
    // tile t+1's loads (issued during t-1) must be landed; the newest 4
    // (tile t+2, issued this tile) stay in flight across the barrier.
    if (t < 30) {
      asm volatile("s_waitcnt vmcnt(4)" ::: "memory");
    } else if (t == 30) {
      asm volatile("s_waitcnt vmcnt(0)" ::: "memory");
    }
    __builtin_amdgcn_s_barrier();
  }

  if (MODE == 0) {
    _Float16* Lh = (_Float16*)sh;  // [64][264] fp16 per phase (padded)
    const float lsc = 0.125f * 1.44269504088896f;
    #pragma unroll
    for (int p = 0; p < 4; p++) {
      if (wm == (p >> 1)) {
        #pragma unroll
        for (int nt = 0; nt < 4; nt++) {
          const int cl = wn * 64 + nt * 16 + mm;
          const float s = sb[(m0 >> 12) * DIM + n0 + cl] * lsc;
          #pragma unroll
          for (int mtl = 0; mtl < 4; mtl++) {
            const int mt = (p & 1) * 4 + mtl;
            const int rl = mtl * 16 + q4 * 4;
            #pragma unroll
            for (int r = 0; r < 4; r++)
              Lh[(rl + r) * 264 + cl] = (_Float16)(acc[mt][nt][r] * s);
          }
        }
      }
      __syncthreads();
      const int row_l = tid >> 3, c0 = (tid & 7) * 32;
      _Float16* dst = (_Float16*)Cout + (size_t)(m0 + p * 64 + row_l) * DIM + n0 + c0;
      #pragma unroll
      for (int i = 0; i < 4; i++)
        *(half8*)(dst + i * 8) = *(half8*)(Lh + row_l * 264 + c0 + i * 8);
      __syncthreads();
    }
  } else {
    float* Lf = (float*)sh;  // [32][260] f32 per phase (padded)
    #pragma unroll
    for (int p = 0; p < 8; p++) {
      if (wm == (p >> 2)) {
        #pragma unroll
        for (int nt = 0; nt < 4; nt++) {
          const int cl = wn * 64 + nt * 16 + mm;
          const float s = sb[n0 + cl];
          #pragma unroll
          for (int mtl = 0; mtl < 2; mtl++) {
            const int mt = (p & 3) * 2 + mtl;
            const int rl = mtl * 16 + q4 * 4;
            #pragma unroll
            for (int r = 0; r < 4; r++)
              Lf[(rl + r) * 260 + cl] = acc[mt][nt][r] + s;
          }
        }
      }
      __syncthreads();
      const int row_l = tid >> 4, c0 = (tid & 15) * 16;
      float* dst = (float*)Cout + (size_t)(m0 + p * 32 + row_l) * DIM + n0 + c0;
      #pragma unroll
      for (int i = 0; i < 4; i++)
        *(f32x4*)(dst + i * 4) = *(f32x4*)(Lf + row_l * 260 + c0 + i * 4);
      __syncthreads();
    }
  }
}

// ---- fused attention v4: grid (8,64)=512 blocks, 8 tiles/wave ----
// DPP row_ror butterflies for the 16-lane softmax reductions (VALU latency,
// not ds_bpermute's ~120cyc); P normalization deferred to the epilogue
// (out linear in P; phase-1/phase-2 C-layout row mapping identical).
__global__ __launch_bounds__(256) void k_attn(const _Float16* __restrict__ Q,
                                              const _Float16* __restrict__ E,
                                              const _Float16* __restrict__ Ftp,
                                              const float* __restrict__ Sv,
                                              _Float16* __restrict__ O) {
  __shared__ _Float16 Ps[4][16][264];
  const int tid = threadIdx.x;
  const int w = tid >> 6, lane = tid & 63;
  const int q4 = lane >> 4, mm = lane & 15;
  const int bh = blockIdx.y;
  const int b = bh >> 4, h = bh & 15;
  const int row_base = blockIdx.x * 512 + w * 128;  // 8 tiles of 16 rows

  half8 ef[16][2];
  #pragma unroll
  for (int t = 0; t < 16; t++)
    #pragma unroll
    for (int kk = 0; kk < 2; kk++)
      ef[t][kk] = *(const half8*)(E + (t * 16 + mm) * HD + kk * 32 + q4 * 8);
  half8 ff[4][8];
  #pragma unroll
  for (int nt = 0; nt < 4; nt++)
    #pragma unroll
    for (int kk = 0; kk < 8; kk++)
      ff[nt][kk] = *(const half8*)(Ftp + (nt * 16 + mm) * KP + kk * 32 + q4 * 8);
  float sv[4];
  #pragma unroll
  for (int nt = 0; nt < 4; nt++) sv[nt] = Sv[b * DIM + h * HD + nt * 16 + mm];

  const _Float16* Qbase = Q + ((size_t)(b * SEQ + row_base + mm)) * DIM + h * HD + q4 * 8;
  half8 qa0 = *(const half8*)(Qbase);
  half8 qa1 = *(const half8*)(Qbase + 32);

  for (int tile = 0; tile < 8; tile++) {
    f32x4 acc[16] = {};
    #pragma unroll
    for (int t = 0; t < 16; t++)
      acc[t] = __builtin_amdgcn_mfma_f32_16x16x32_f16(qa0, ef[t][0], acc[t], 0, 0, 0);
    #pragma unroll
    for (int t = 0; t < 16; t++)
      acc[t] = __builtin_amdgcn_mfma_f32_16x16x32_f16(qa1, ef[t][1], acc[t], 0, 0, 0);
    half8 qn0, qn1;
    if (tile < 7) {
      const _Float16* Qn = Qbase + (size_t)(tile + 1) * 16 * DIM;
      qn0 = *(const half8*)(Qn);
      qn1 = *(const half8*)(Qn + 32);
    }
    // rowwise max over 256 cols (base-2 logits; log2e folded upstream)
    float mx[4] = {-1e30f, -1e30f, -1e30f, -1e30f};
    #pragma unroll
    for (int t = 0; t < 16; t++)
      #pragma unroll
      for (int r = 0; r < 4; r++) mx[r] = fmaxf(mx[r], acc[t][r]);
    #pragma unroll
    for (int r = 0; r < 4; r++) {
      float m = mx[r];
      m = fmaxf(m, DPPF(m, 0x121));  // row_ror:1
      m = fmaxf(m, DPPF(m, 0x122));  // row_ror:2
      m = fmaxf(m, DPPF(m, 0x124));  // row_ror:4
      m = fmaxf(m, DPPF(m, 0x128));  // row_ror:8
      mx[r] = m;
    }
    float sm[4] = {0.f, 0.f, 0.f, 0.f};
    #pragma unroll
    for (int t = 0; t < 16; t++)
      #pragma unroll
      for (int r = 0; r < 4; r++) {
        float p = __builtin_amdgcn_exp2f(acc[t][r] - mx[r]);
        acc[t][r] = p;
        sm[r] += p;
      }
    #pragma unroll
    for (int r = 0; r < 4; r++) {
      float s = sm[r];
      s += DPPF(s, 0x121);
      s += DPPF(s, 0x122);
      s += DPPF(s, 0x124);
      s += DPPF(s, 0x128);
      sm[r] = 1.f / s;
    }
    // unnormalized P -> LDS (permuted-col layout; normalize in epilogue)
    #pragma unroll
    for (int r = 0; r < 4; r++) {
      half8 h0, h1;
      #pragma unroll
      for (int t = 0; t < 8; t++) h0[t] = (_Float16)acc[t][r];
      #pragma unroll
      for (int t = 0; t < 8; t++) h1[t] = (_Float16)acc[t + 8][r];
      *(half8*)&Ps[w][q4 * 4 + r][mm * 16] = h0;
      *(half8*)&Ps[w][q4 * 4 + r][mm * 16 + 8] = h1;
    }
    // phase 2: out = P @ F (permuted k-order), scale by sm[r]*sv[nt] at write
    f32x4 acc2[4] = {};
    #pragma unroll
    for (int kk = 0; kk < 8; kk++) {
      half8 pa = *(const half8*)&Ps[w][mm][kk * 32 + q4 * 8];
      #pragma unroll
      for (int nt = 0; nt < 4; nt++)
        acc2[nt] = __builtin_amdgcn_mfma_f32_16x16x32_f16(pa, ff[nt][kk], acc2[nt], 0, 0, 0);
    }
    const int rw0 = row_base + tile * 16;
    #pragma unroll
    for (int nt = 0; nt < 4; nt++)
      #pragma unroll
      for (int r = 0; r < 4; r++)
        O[(size_t)(b * SEQ + rw0 + q4 * 4 + r) * DIM + h * HD + nt * 16 + mm] =
            (_Float16)(acc2[nt][r] * (sm[r] * sv[nt]));
    qa0 = qn0;
    qa1 = qn1;
  }
}

extern "C" void kernel_launch(void* const* d_in, const int* in_sizes, int n_in,
                              void* d_out, int out_size, void* d_ws, size_t ws_size,
                              hipStream_t stream) {
  (void)in_sizes; (void)n_in; (void)out_size; (void)ws_size;
  const float* x  = (const float*)d_in[0];
  const float* Wq = (const float*)d_in[1];
  const float* Wk = (const float*)d_in[2];
  const float* Wv = (const float*)d_in[3];
  const float* E  = (const float*)d_in[4];
  const float* F  = (const float*)d_in[5];
  const float* Wo = (const float*)d_in[6];
  const float* bo = (const float*)d_in[7];
  char* ws = (char*)d_ws;
  _Float16* x_h  = (_Float16*)(ws);
  _Float16* O_h  = (_Float16*)(ws);          // aliases x_h (dead after Q GEMM)
  _Float16* Q_h  = (_Float16*)(ws + 33554432);
  _Float16* Wq_h = (_Float16*)(ws + 67108864);
  _Float16* Wo_h = (_Float16*)(ws + 69206016);
  _Float16* E_h  = (_Float16*)(ws + 71303168);
  _Float16* Ft_h = (_Float16*)(ws + 71335936);
  float* xsum    = (float*)(ws + 71368704);
  float* Sk      = (float*)(ws + 71385088);
  float* Sv      = (float*)(ws + 71401472);
  float* out     = (float*)d_out;

  k_cvt<<<8192, 256, 0, stream>>>(x, x_h);
  k_misc<<<88, 256, 0, stream>>>(E, F, E_h, Ft_h, xsum);
  k_cvtw<<<1024, 256, 0, stream>>>(Wq, Wo, Wq_h, Wo_h);
  k_xsum<<<dim3(4, BATCH, 32), 256, 0, stream>>>(x_h, xsum);
  k_sksv<<<2048, 256, 0, stream>>>(xsum, Wk, Wv, Sk, Sv);
  k_gemm<0><<<dim3(64, 4), 512, 0, stream>>>(x_h, Wq_h, (void*)Q_h, Sk);
  k_attn<<<dim3(8, 64), 256, 0, stream>>>(Q_h, E_h, Ft_h, Sv, O_h);
  k_gemm<1><<<dim3(64, 4), 512, 0, stream>>>(O_h, Wo_h, (void*)out, bo);
}

// Round 4
// 293.595 us; speedup vs baseline: 1.0194x; 1.0194x over previous
//
#include <hip/hip_runtime.h>

#define DIM 1024
#define BATCH 4
#define SEQ 4096
#define NH 16
#define HD 64
#define KP 256

typedef float f32x4 __attribute__((ext_vector_type(4)));
typedef _Float16 half8 __attribute__((ext_vector_type(8)));
typedef int i32x4 __attribute__((ext_vector_type(4)));

__device__ __forceinline__ void gll16(const void* g, void* l) {
  __builtin_amdgcn_global_load_lds(
      (const __attribute__((address_space(1))) void*)g,
      (__attribute__((address_space(3))) void*)l, 16, 0, 0);
}

__device__ __forceinline__ unsigned lds_addr(const void* p) {
  return (unsigned)(size_t)(const __attribute__((address_space(3))) void*)p;
}

// Inline-asm ds_read_b128: opaque to alias analysis, so the compiler cannot
// order it against in-flight global_load_lds writes (round-3 postmortem: the
// compiler's conservative vmcnt(0) before the half8 LDS loads serialized
// every tile). Ordering vs staging is enforced by our explicit vmcnt+barrier.
#define DSR128(dst, base, imm)                                               \
  asm volatile("ds_read_b128 %0, %1 offset:" #imm : "=&v"(dst) : "v"(base))

// DPP row_ror:n within 16-lane rows (VALU-latency cross-lane; our reduction
// groups are exactly the 16-lane DPP rows). ctrl = 0x120|n.
#define DPPF(v, ctrl)                                                        \
  __builtin_bit_cast(float, __builtin_amdgcn_mov_dpp(                        \
                                __builtin_bit_cast(int, v), ctrl, 0xF, 0xF, true))

// ---- fp32 -> fp16 elementwise convert, 8 elems/thread ----
__global__ void k_cvt(const float* __restrict__ s, _Float16* __restrict__ d) {
  int i = (blockIdx.x * 256 + threadIdx.x) * 8;
  f32x4 a = *(const f32x4*)(s + i);
  f32x4 b = *(const f32x4*)(s + i + 4);
  half8 h;
  h[0] = a[0]; h[1] = a[1]; h[2] = a[2]; h[3] = a[3];
  h[4] = b[0]; h[5] = b[1]; h[6] = b[2]; h[7] = b[3];
  *(half8*)(d + i) = h;
}

// Wq and Wo converts merged: grid 1024 blocks
__global__ void k_cvtw(const float* __restrict__ Wq, const float* __restrict__ Wo,
                       _Float16* __restrict__ Wq_h, _Float16* __restrict__ Wo_h) {
  int bb = blockIdx.x;
  const float* s = (bb < 512) ? Wq : Wo;
  _Float16* d = (bb < 512) ? Wq_h : Wo_h;
  int i = ((bb & 511) * 256 + threadIdx.x) * 8;
  f32x4 a = *(const f32x4*)(s + i);
  f32x4 b = *(const f32x4*)(s + i + 4);
  half8 h;
  h[0] = a[0]; h[1] = a[1]; h[2] = a[2]; h[3] = a[3];
  h[4] = b[0]; h[5] = b[1]; h[6] = b[2]; h[7] = b[3];
  *(half8*)(d + i) = h;
}

// misc small work merged: grid 88 blocks
__global__ void k_misc(const float* __restrict__ E, const float* __restrict__ F,
                       _Float16* __restrict__ E_h, _Float16* __restrict__ Ft,
                       float* __restrict__ xsum) {
  int bb = blockIdx.x;
  if (bb < 16) {
    xsum[bb * 256 + threadIdx.x] = 0.f;
  } else if (bb < 24) {
    int i = ((bb - 16) * 256 + threadIdx.x) * 8;
    f32x4 a = *(const f32x4*)(E + i);
    f32x4 b = *(const f32x4*)(E + i + 4);
    half8 h;
    h[0] = a[0]; h[1] = a[1]; h[2] = a[2]; h[3] = a[3];
    h[4] = b[0]; h[5] = b[1]; h[6] = b[2]; h[7] = b[3];
    *(half8*)(E_h + i) = h;
  } else {
    int i = (bb - 24) * 256 + threadIdx.x;  // 16384
    int k = i >> 6, d = i & 63;
    Ft[d * KP + (k & 15) * 16 + (k >> 4)] = (_Float16)F[i];
  }
}

// xsum[b,c] = sum_n x[b,n,c]; reads fp16 x_h; grid (4,B,32)
__global__ void k_xsum(const _Float16* __restrict__ xh, float* __restrict__ xs) {
  int c = blockIdx.x * 256 + threadIdx.x;
  int b = blockIdx.y;
  int n0 = blockIdx.z * 128;
  const _Float16* p = xh + (size_t)(b * SEQ + n0) * DIM + c;
  float s = 0.f;
  #pragma unroll 8
  for (int i = 0; i < 128; i++) s += (float)p[i * DIM];
  atomicAdd(&xs[b * DIM + c], s);
}

// Sk[b,c] = xsum[b,:]@Wk[c,:], Sv likewise. One wave per output dot.
__global__ void k_sksv(const float* __restrict__ xs, const float* __restrict__ Wk,
                       const float* __restrict__ Wv, float* __restrict__ Sk,
                       float* __restrict__ Sv) {
  int idx = blockIdx.x * 4 + (threadIdx.x >> 6);
  int lane = threadIdx.x & 63;
  int kv = idx >> 12;
  int rem = idx & 4095;
  int b = rem >> 10, c = rem & 1023;
  const float* W = (kv ? Wv : Wk) + c * DIM;
  const float* xp = xs + b * DIM;
  float a = 0.f;
  #pragma unroll
  for (int i = 0; i < 16; i++) a += xp[lane + i * 64] * W[lane + i * 64];
  for (int off = 32; off; off >>= 1) a += __shfl_down(a, off);
  if (lane == 0) (kv ? Sv : Sk)[rem] = a;
}

// ---- fp16 MFMA GEMM, round 6: asm ds_read fragments ----
// Round-3/4/5 postmortem: schedule edits (phases, counted vmcnt, setprio)
// plateaued at 57-70us because the compiler — unable to prove the ring
// buffers disjoint from the gll16 destinations — conservatively drained
// vmcnt before the HIP-level LDS loads inside EVERY tile (full load latency
// on the critical path). This round: fragment reads are inline-asm
// ds_read_b128 (opaque to alias analysis); ordering vs staging is OURS:
// end-of-tile vmcnt(4)+s_barrier guarantees tile t's data landed before its
// reads, and in-flight writes target buf (t+2)&3 != t&3. Rule-18 fence
// (lgkmcnt(0)+sched_barrier(0)) between reads and MFMA block.
// MODE 0: out fp16 = acc * sb[b*DIM+col] * 0.125 * log2e  (Q proj)
// MODE 1: out fp32 = acc + sb[col]                        (out proj + bias)
template <int MODE>
__global__ __launch_bounds__(512, 2) void k_gemm(const _Float16* __restrict__ A,
                                                 const _Float16* __restrict__ Bw,
                                                 void* __restrict__ Cout,
                                                 const float* __restrict__ sb) {
  __shared__ _Float16 sh[4][2][8192];  // [ring][A=0/B=1][256 rows x 32 k]
  const int tid = threadIdx.x;
  const int w = tid >> 6, l = tid & 63;
  const int q4 = l >> 4, mm = l & 15;
  const int wm = w & 1, wn = w >> 1;
  const int m0 = blockIdx.x * 256, n0 = blockIdx.y * 256;
  f32x4 acc[8][4] = {};

  // staging: lds chunk c = w*128+u*64+l -> row=c>>2, chunk=c&3; source is
  // pre-swizzled so LDS[row][c] = global[row][c ^ ((row>>1)&3)].
  const int schunk = ((l & 3) ^ ((l >> 3) & 3)) * 8;
  const _Float16* Ag = A + (size_t)(m0 + w * 32 + (l >> 2)) * DIM + schunk;
  const _Float16* Bg = Bw + (size_t)(n0 + w * 32 + (l >> 2)) * DIM + schunk;
  const int sdst = w * 1024;
  // reader: global chunk q4 of row r is stored at chunk q4 ^ ((r>>1)&3);
  // (r>>1)&3 == (mm>>1)&3 for all frag rows.
  const int csw = (q4 ^ ((mm >> 1) & 3)) * 8;
  const unsigned shb = lds_addr(&sh[0][0][0]);
  const unsigned ab0 = shb + (unsigned)(((wm * 128 + mm) * 32 + csw) * 2);
  const unsigned bb0 = shb + 16384u + (unsigned)(((wn * 64 + mm) * 32 + csw) * 2);

  // prologue: stage K-tiles 0 and 1; wait tile 0 only (4 newest in flight)
  gll16(Ag, &sh[0][0][sdst]);
  gll16(Ag + 16 * DIM, &sh[0][0][sdst + 512]);
  gll16(Bg, &sh[0][1][sdst]);
  gll16(Bg + 16 * DIM, &sh[0][1][sdst + 512]);
  gll16(Ag + 32, &sh[1][0][sdst]);
  gll16(Ag + 32 + 16 * DIM, &sh[1][0][sdst + 512]);
  gll16(Bg + 32, &sh[1][1][sdst]);
  gll16(Bg + 32 + 16 * DIM, &sh[1][1][sdst + 512]);
  asm volatile("s_waitcnt vmcnt(4)" ::: "memory");
  __builtin_amdgcn_s_barrier();

  #pragma unroll 4
  for (int t = 0; t < 32; t++) {
    const int s = t & 3, rs = (t + 2) & 3;
    // stage tile t+2 first: vmem queue starts earliest
    if (t < 30) {
      const int kn = (t + 2) * 32;
      gll16(Ag + kn, &sh[rs][0][sdst]);
      gll16(Ag + kn + 16 * DIM, &sh[rs][0][sdst + 512]);
      gll16(Bg + kn, &sh[rs][1][sdst]);
      gll16(Bg + kn + 16 * DIM, &sh[rs][1][sdst + 512]);
    }
    const unsigned ab = ab0 + (unsigned)(s * 32768);
    const unsigned bb = bb0 + (unsigned)(s * 32768);
    i32x4 ar[8], br[4];
    DSR128(br[0], bb, 0);
    DSR128(br[1], bb, 1024);
    DSR128(br[2], bb, 2048);
    DSR128(br[3], bb, 3072);
    DSR128(ar[0], ab, 0);
    DSR128(ar[1], ab, 1024);
    DSR128(ar[2], ab, 2048);
    DSR128(ar[3], ab, 3072);
    DSR128(ar[4], ab, 4096);
    DSR128(ar[5], ab, 5120);
    DSR128(ar[6], ab, 6144);
    DSR128(ar[7], ab, 7168);
    asm volatile("s_waitcnt lgkmcnt(0)" ::: "memory");
    __builtin_amdgcn_sched_barrier(0);
    __builtin_amdgcn_s_setprio(1);
    #pragma unroll
    for (int mt = 0; mt < 8; mt++)
      #pragma unroll
      for (int nt = 0; nt < 4; nt++)
        acc[mt][nt] = __builtin_amdgcn_mfma_f32_16x16x32_f16(
            __builtin_bit_cast(half8, ar[mt]), __builtin_bit_cast(half8, br[nt]),
            acc[mt][nt], 0, 0, 0);
    __builtin_amdgcn_s_setprio(0);
    // tile t+1's loads (issued during t-1) must be landed; the newest 4
    // (tile t+2, issued this tile) stay in flight across the barrier.
    if (t < 30) {
      asm volatile("s_waitcnt vmcnt(4)" ::: "memory");
    } else if (t == 30) {
      asm volatile("s_waitcnt vmcnt(0)" ::: "memory");
    }
    __builtin_amdgcn_s_barrier();
  }

  if (MODE == 0) {
    _Float16* Lh = (_Float16*)sh;  // [64][264] fp16 per phase (padded)
    const float lsc = 0.125f * 1.44269504088896f;
    #pragma unroll
    for (int p = 0; p < 4; p++) {
      if (wm == (p >> 1)) {
        #pragma unroll
        for (int nt = 0; nt < 4; nt++) {
          const int cl = wn * 64 + nt * 16 + mm;
          const float s = sb[(m0 >> 12) * DIM + n0 + cl] * lsc;
          #pragma unroll
          for (int mtl = 0; mtl < 4; mtl++) {
            const int mt = (p & 1) * 4 + mtl;
            const int rl = mtl * 16 + q4 * 4;
            #pragma unroll
            for (int r = 0; r < 4; r++)
              Lh[(rl + r) * 264 + cl] = (_Float16)(acc[mt][nt][r] * s);
          }
        }
      }
      __syncthreads();
      const int row_l = tid >> 3, c0 = (tid & 7) * 32;
      _Float16* dst = (_Float16*)Cout + (size_t)(m0 + p * 64 + row_l) * DIM + n0 + c0;
      #pragma unroll
      for (int i = 0; i < 4; i++)
        *(half8*)(dst + i * 8) = *(half8*)(Lh + row_l * 264 + c0 + i * 8);
      __syncthreads();
    }
  } else {
    float* Lf = (float*)sh;  // [32][260] f32 per phase (padded)
    #pragma unroll
    for (int p = 0; p < 8; p++) {
      if (wm == (p >> 2)) {
        #pragma unroll
        for (int nt = 0; nt < 4; nt++) {
          const int cl = wn * 64 + nt * 16 + mm;
          const float s = sb[n0 + cl];
          #pragma unroll
          for (int mtl = 0; mtl < 2; mtl++) {
            const int mt = (p & 3) * 2 + mtl;
            const int rl = mtl * 16 + q4 * 4;
            #pragma unroll
            for (int r = 0; r < 4; r++)
              Lf[(rl + r) * 260 + cl] = acc[mt][nt][r] + s;
          }
        }
      }
      __syncthreads();
      const int row_l = tid >> 4, c0 = (tid & 15) * 16;
      float* dst = (float*)Cout + (size_t)(m0 + p * 32 + row_l) * DIM + n0 + c0;
      #pragma unroll
      for (int i = 0; i < 4; i++)
        *(f32x4*)(dst + i * 4) = *(f32x4*)(Lf + row_l * 260 + c0 + i * 4);
      __syncthreads();
    }
  }
}

// ---- fused attention v4: grid (8,64)=512 blocks, 8 tiles/wave ----
// DPP row_ror butterflies for the 16-lane softmax reductions (VALU latency,
// not ds_bpermute's ~120cyc); P normalization deferred to the epilogue
// (out linear in P; phase-1/phase-2 C-layout row mapping identical).
__global__ __launch_bounds__(256) void k_attn(const _Float16* __restrict__ Q,
                                              const _Float16* __restrict__ E,
                                              const _Float16* __restrict__ Ftp,
                                              const float* __restrict__ Sv,
                                              _Float16* __restrict__ O) {
  __shared__ _Float16 Ps[4][16][264];
  const int tid = threadIdx.x;
  const int w = tid >> 6, lane = tid & 63;
  const int q4 = lane >> 4, mm = lane & 15;
  const int bh = blockIdx.y;
  const int b = bh >> 4, h = bh & 15;
  const int row_base = blockIdx.x * 512 + w * 128;  // 8 tiles of 16 rows

  half8 ef[16][2];
  #pragma unroll
  for (int t = 0; t < 16; t++)
    #pragma unroll
    for (int kk = 0; kk < 2; kk++)
      ef[t][kk] = *(const half8*)(E + (t * 16 + mm) * HD + kk * 32 + q4 * 8);
  half8 ff[4][8];
  #pragma unroll
  for (int nt = 0; nt < 4; nt++)
    #pragma unroll
    for (int kk = 0; kk < 8; kk++)
      ff[nt][kk] = *(const half8*)(Ftp + (nt * 16 + mm) * KP + kk * 32 + q4 * 8);
  float sv[4];
  #pragma unroll
  for (int nt = 0; nt < 4; nt++) sv[nt] = Sv[b * DIM + h * HD + nt * 16 + mm];

  const _Float16* Qbase = Q + ((size_t)(b * SEQ + row_base + mm)) * DIM + h * HD + q4 * 8;
  half8 qa0 = *(const half8*)(Qbase);
  half8 qa1 = *(const half8*)(Qbase + 32);

  for (int tile = 0; tile < 8; tile++) {
    f32x4 acc[16] = {};
    #pragma unroll
    for (int t = 0; t < 16; t++)
      acc[t] = __builtin_amdgcn_mfma_f32_16x16x32_f16(qa0, ef[t][0], acc[t], 0, 0, 0);
    #pragma unroll
    for (int t = 0; t < 16; t++)
      acc[t] = __builtin_amdgcn_mfma_f32_16x16x32_f16(qa1, ef[t][1], acc[t], 0, 0, 0);
    half8 qn0, qn1;
    if (tile < 7) {
      const _Float16* Qn = Qbase + (size_t)(tile + 1) * 16 * DIM;
      qn0 = *(const half8*)(Qn);
      qn1 = *(const half8*)(Qn + 32);
    }
    // rowwise max over 256 cols (base-2 logits; log2e folded upstream)
    float mx[4] = {-1e30f, -1e30f, -1e30f, -1e30f};
    #pragma unroll
    for (int t = 0; t < 16; t++)
      #pragma unroll
      for (int r = 0; r < 4; r++) mx[r] = fmaxf(mx[r], acc[t][r]);
    #pragma unroll
    for (int r = 0; r < 4; r++) {
      float m = mx[r];
      m = fmaxf(m, DPPF(m, 0x121));  // row_ror:1
      m = fmaxf(m, DPPF(m, 0x122));  // row_ror:2
      m = fmaxf(m, DPPF(m, 0x124));  // row_ror:4
      m = fmaxf(m, DPPF(m, 0x128));  // row_ror:8
      mx[r] = m;
    }
    float sm[4] = {0.f, 0.f, 0.f, 0.f};
    #pragma unroll
    for (int t = 0; t < 16; t++)
      #pragma unroll
      for (int r = 0; r < 4; r++) {
        float p = __builtin_amdgcn_exp2f(acc[t][r] - mx[r]);
        acc[t][r] = p;
        sm[r] += p;
      }
    #pragma unroll
    for (int r = 0; r < 4; r++) {
      float s = sm[r];
      s += DPPF(s, 0x121);
      s += DPPF(s, 0x122);
      s += DPPF(s, 0x124);
      s += DPPF(s, 0x128);
      sm[r] = 1.f / s;
    }
    // unnormalized P -> LDS (permuted-col layout; normalize in epilogue)
    #pragma unroll
    for (int r = 0; r < 4; r++) {
      half8 h0, h1;
      #pragma unroll
      for (int t = 0; t < 8; t++) h0[t] = (_Float16)acc[t][r];
      #pragma unroll
      for (int t = 0; t < 8; t++) h1[t] = (_Float16)acc[t + 8][r];
      *(half8*)&Ps[w][q4 * 4 + r][mm * 16] = h0;
      *(half8*)&Ps[w][q4 * 4 + r][mm * 16 + 8] = h1;
    }
    // phase 2: out = P @ F (permuted k-order), scale by sm[r]*sv[nt] at write
    f32x4 acc2[4] = {};
    #pragma unroll
    for (int kk = 0; kk < 8; kk++) {
      half8 pa = *(const half8*)&Ps[w][mm][kk * 32 + q4 * 8];
      #pragma unroll
      for (int nt = 0; nt < 4; nt++)
        acc2[nt] = __builtin_amdgcn_mfma_f32_16x16x32_f16(pa, ff[nt][kk], acc2[nt], 0, 0, 0);
    }
    const int rw0 = row_base + tile * 16;
    #pragma unroll
    for (int nt = 0; nt < 4; nt++)
      #pragma unroll
      for (int r = 0; r < 4; r++)
        O[(size_t)(b * SEQ + rw0 + q4 * 4 + r) * DIM + h * HD + nt * 16 + mm] =
            (_Float16)(acc2[nt][r] * (sm[r] * sv[nt]));
    qa0 = qn0;
    qa1 = qn1;
  }
}

extern "C" void kernel_launch(void* const* d_in, const int* in_sizes, int n_in,
                              void* d_out, int out_size, void* d_ws, size_t ws_size,
                              hipStream_t stream) {
  (void)in_sizes; (void)n_in; (void)out_size; (void)ws_size;
  const float* x  = (const float*)d_in[0];
  const float* Wq = (const float*)d_in[1];
  const float* Wk = (const float*)d_in[2];
  const float* Wv = (const float*)d_in[3];
  const float* E  = (const float*)d_in[4];
  const float* F  = (const float*)d_in[5];
  const float* Wo = (const float*)d_in[6];
  const float* bo = (const float*)d_in[7];
  char* ws = (char*)d_ws;
  _Float16* x_h  = (_Float16*)(ws);
  _Float16* O_h  = (_Float16*)(ws);          // aliases x_h (dead after Q GEMM)
  _Float16* Q_h  = (_Float16*)(ws + 33554432);
  _Float16* Wq_h = (_Float16*)(ws + 67108864);
  _Float16* Wo_h = (_Float16*)(ws + 69206016);
  _Float16* E_h  = (_Float16*)(ws + 71303168);
  _Float16* Ft_h = (_Float16*)(ws + 71335936);
  float* xsum    = (float*)(ws + 71368704);
  float* Sk      = (float*)(ws + 71385088);
  float* Sv      = (float*)(ws + 71401472);
  float* out     = (float*)d_out;

  k_cvt<<<8192, 256, 0, stream>>>(x, x_h);
  k_misc<<<88, 256, 0, stream>>>(E, F, E_h, Ft_h, xsum);
  k_cvtw<<<1024, 256, 0, stream>>>(Wq, Wo, Wq_h, Wo_h);
  k_xsum<<<dim3(4, BATCH, 32), 256, 0, stream>>>(x_h, xsum);
  k_sksv<<<2048, 256, 0, stream>>>(xsum, Wk, Wv, Sk, Sv);
  k_gemm<0><<<dim3(64, 4), 512, 0, stream>>>(x_h, Wq_h, (void*)Q_h, Sk);
  k_attn<<<dim3(8, 64), 256, 0, stream>>>(Q_h, E_h, Ft_h, Sv, O_h);
  k_gemm<1><<<dim3(64, 4), 512, 0, stream>>>(O_h, Wo_h, (void*)out, bo);
}